// Round 4
// baseline (307.198 us; speedup 1.0000x reference)
//
#include <hip/hip_runtime.h>
#include <hip/hip_bf16.h>

#define MASK_ID 3
#define MAX_SEN 128
#define NB 8
#define SEQ 8192
#define EMB 1024
#define DIM 128

typedef __attribute__((ext_vector_type(8))) short short8v;   // 8 bf16
typedef __attribute__((ext_vector_type(4))) short short4v;   // 4 bf16
typedef __attribute__((ext_vector_type(4))) float f32x4;     // MFMA accumulator

#define MFMA(a, b, c) __builtin_amdgcn_mfma_f32_16x16x32_bf16(a, b, c, 0, 0, 0)

// fp32 -> bf16 (round-nearest-even), raw short
__device__ __forceinline__ short f2b(float x) {
    union { float f; unsigned u; } v; v.f = x;
    unsigned r = (v.u + 0x7FFFu + ((v.u >> 16) & 1u)) >> 16;
    return (short)r;
}

// ---------------- Kernel 1: per-row scan -> mask positions + nvis ----------------
__global__ __launch_bounds__(1024) void seg_kernel(const int* __restrict__ ids,
                                                   int* __restrict__ pos,
                                                   int* __restrict__ nvis) {
    int b = blockIdx.x;
    int tid = threadIdx.x;
    __shared__ int sc[1024];
    __shared__ int sc2[1024];
    const int PER = SEQ / 1024;  // 8
    int base = b * SEQ + tid * PER;

    int ids_l[PER];
    int cnt = 0;
    #pragma unroll
    for (int j = 0; j < PER; j++) {
        ids_l[j] = ids[base + j];
        cnt += (ids_l[j] == MASK_ID) ? 1 : 0;
    }
    if (tid < MAX_SEN) pos[b * MAX_SEN + tid] = -1;
    sc[tid] = cnt;
    __syncthreads();

    int* src = sc;
    int* dst = sc2;
    for (int off = 1; off < 1024; off <<= 1) {
        int v = src[tid];
        if (tid >= off) v += src[tid - off];
        dst[tid] = v;
        __syncthreads();
        int* t = src; src = dst; dst = t;
    }
    int incl = src[tid];
    int run = incl - cnt;  // exclusive prefix

    #pragma unroll
    for (int j = 0; j < PER; j++) {
        if (ids_l[j] == MASK_ID) {
            run++;
            if (run <= MAX_SEN) pos[b * MAX_SEN + run - 1] = tid * PER + j;
        }
        int nv = run; if (nv > MAX_SEN) nv = MAX_SEN;
        nvis[base + j] = nv;
    }
}

// ---------------- Kernel 2: transpose+convert weights to bf16 ----------------
__global__ __launch_bounds__(256) void prep_w(const float* __restrict__ Wq,
                                              const float* __restrict__ Wo,
                                              short* __restrict__ WqT,
                                              short* __restrict__ WoT) {
    int idx = blockIdx.x * 256 + threadIdx.x;      // 0 .. 131071
    int d = idx >> 10, e = idx & 1023;
    WqT[idx] = f2b(Wq[e * DIM + d]);
    int e2 = idx >> 7, d2 = idx & 127;
    WoT[idx] = f2b(Wo[d2 * EMB + e2]);
}

// ---------------- Kernel 3: fused static+kv: k_bf[m][d], vT_bf[d][m] ----------------
__global__ __launch_bounds__(128) void statkv_kernel(const float* __restrict__ hidden,
                                                     const float* __restrict__ Wv, const float* __restrict__ bv,
                                                     const float* __restrict__ Wk, const float* __restrict__ bk,
                                                     const float* __restrict__ Wvt, const float* __restrict__ bvt,
                                                     const int* __restrict__ pos,
                                                     short* __restrict__ k_bf, short* __restrict__ vT_bf) {
    int m = blockIdx.x, b = blockIdx.y;
    int d = threadIdx.x;
    __shared__ float h[EMB];
    __shared__ float srow[DIM];
    int p = pos[b * MAX_SEN + m];   // uniform across block
    float acc = bv[d];
    if (p >= 0) {
        const float* hp = hidden + ((size_t)b * SEQ + p) * EMB;
        for (int e = d; e < EMB; e += 128) h[e] = hp[e];
        __syncthreads();
        for (int e = 0; e < EMB; e++) acc += h[e] * Wv[e * DIM + d];
    }
    srow[d] = acc;
    __syncthreads();
    float ka = bk[d], va = bvt[d];
    for (int e = 0; e < DIM; e++) {
        float sv = srow[e];
        ka += sv * Wk[e * DIM + d];
        va += sv * Wvt[e * DIM + d];
    }
    k_bf[((size_t)b * MAX_SEN + m) * DIM + d] = f2b(ka);
    vT_bf[((size_t)b * DIM + d) * MAX_SEN + m] = f2b(va);
}

// ---------------- Kernel 4: q-projection streaming GEMM ----------------
// 64 rows per block, 4 waves; wave w owns q-cols [w*32, w*32+32) -> WqT read once/block.
__global__ __launch_bounds__(256, 4) void q_kernel(const float* __restrict__ hidden,
                                                   const short* __restrict__ WqT,
                                                   const float* __restrict__ bq,
                                                   short* __restrict__ q_bf) {
    int blk = blockIdx.x;            // 1024 blocks
    size_t r0 = (size_t)blk * 64;
    int tid = threadIdx.x;
    int lane = tid & 63, w = tid >> 6, lr = lane & 15, lq = lane >> 4;

    __shared__ char hAc[64 * 256];   // 64 rows x 128 bf16, swizzled 256B rows

    f32x4 acc[4][2];
    #pragma unroll
    for (int rg = 0; rg < 4; rg++)
        #pragma unroll
        for (int cf = 0; cf < 2; cf++) acc[rg][cf] = {0.f, 0.f, 0.f, 0.f};

    // prefetch chunk 0 into regs
    float4 pf[8];
    #pragma unroll
    for (int g = 0; g < 8; g++) {
        int G = g * 256 + tid;
        int row = G >> 5, e4 = (G & 31) << 2;
        pf[g] = *(const float4*)(hidden + (r0 + row) * EMB + e4);
    }

    for (int c = 0; c < 8; c++) {
        __syncthreads();             // previous chunk's readers done
        #pragma unroll
        for (int g = 0; g < 8; g++) {
            int G = g * 256 + tid;
            int row = G >> 5, e4 = (G & 31) << 2;
            short4v hh;
            hh[0] = f2b(pf[g].x); hh[1] = f2b(pf[g].y);
            hh[2] = f2b(pf[g].z); hh[3] = f2b(pf[g].w);
            int byte = (row * 256 + e4 * 2) ^ ((row & 7) << 4);
            *(short4v*)(hAc + byte) = hh;
        }
        if (c < 7) {
            #pragma unroll
            for (int g = 0; g < 8; g++) {
                int G = g * 256 + tid;
                int row = G >> 5, e4 = (G & 31) << 2;
                pf[g] = *(const float4*)(hidden + (r0 + row) * EMB + (c + 1) * 128 + e4);
            }
        }
        __syncthreads();
        #pragma unroll
        for (int kk = 0; kk < 4; kk++) {
            short8v fa[4];
            #pragma unroll
            for (int rg = 0; rg < 4; rg++)
                fa[rg] = *(short8v*)(hAc + (((rg * 16 + lr) * 256 + kk * 64 + lq * 16) ^ ((lr & 7) << 4)));
            #pragma unroll
            for (int cf = 0; cf < 2; cf++) {
                const short8v fb = *(const short8v*)(WqT + (size_t)(w * 32 + cf * 16 + lr) * 1024
                                                     + c * 128 + kk * 32 + lq * 8);
                #pragma unroll
                for (int rg = 0; rg < 4; rg++) acc[rg][cf] = MFMA(fa[rg], fb, acc[rg][cf]);
            }
        }
    }
    const float scale = 0.08838834764831845f;   // 128^-0.5
    #pragma unroll
    for (int cf = 0; cf < 2; cf++) {
        int col = w * 32 + cf * 16 + lr;
        float bqv = bq[col];
        #pragma unroll
        for (int rg = 0; rg < 4; rg++)
            #pragma unroll
            for (int r = 0; r < 4; r++)
                q_bf[(r0 + rg * 16 + lq * 4 + r) * 128 + col] = f2b((acc[rg][cf][r] + bqv) * scale);
    }
}

// ---------------- Kernel 5: logits -> softmax -> PV -> out-proj, 64 tokens/block ----------------
__global__ __launch_bounds__(256, 2) void atto_kernel(const short* __restrict__ q_bf,
                                                      const short* __restrict__ k_bf,
                                                      const short* __restrict__ vT_bf,
                                                      const short* __restrict__ WoT,
                                                      const float* __restrict__ bo,
                                                      const int* __restrict__ nvis,
                                                      float* __restrict__ out) {
    int blk = blockIdx.x;            // 1024
    int b = blk >> 7;                // 128 blocks per batch
    int sl = (blk & 127) * 64;
    size_t s0 = (size_t)b * SEQ + sl;
    int tid = threadIdx.x;
    int lane = tid & 63, w = tid >> 6, lr = lane & 15, lq = lane >> 4;

    __shared__ float lg[64 * 132];   // 33792 B logits
    __shared__ short pP[64 * 128];   // P bf16, swizzled
    __shared__ short odB[64 * 128];  // od bf16, swizzled
    char* pPc = (char*)pP;
    char* odc = (char*)odB;

    // ---- logits: wave w -> sentences [w*32, w*32+32) ----
    {
        f32x4 acc[4][2];
        #pragma unroll
        for (int rg = 0; rg < 4; rg++)
            #pragma unroll
            for (int mf = 0; mf < 2; mf++) acc[rg][mf] = {0.f, 0.f, 0.f, 0.f};
        #pragma unroll
        for (int kk = 0; kk < 4; kk++) {
            short8v fa[4];
            #pragma unroll
            for (int rg = 0; rg < 4; rg++)
                fa[rg] = *(const short8v*)(q_bf + (s0 + rg * 16 + lr) * 128 + kk * 32 + lq * 8);
            #pragma unroll
            for (int mf = 0; mf < 2; mf++) {
                const short8v fb = *(const short8v*)(k_bf + ((size_t)b << 14)
                                                     + (w * 32 + mf * 16 + lr) * 128 + kk * 32 + lq * 8);
                #pragma unroll
                for (int rg = 0; rg < 4; rg++) acc[rg][mf] = MFMA(fa[rg], fb, acc[rg][mf]);
            }
        }
        #pragma unroll
        for (int rg = 0; rg < 4; rg++)
            #pragma unroll
            for (int mf = 0; mf < 2; mf++)
                #pragma unroll
                for (int r = 0; r < 4; r++)
                    lg[(rg * 16 + lq * 4 + r) * 132 + w * 32 + mf * 16 + lr] = acc[rg][mf][r];
    }
    __syncthreads();

    // ---- masked softmax: 4 threads per token, 32 sentences each ----
    {
        int t = tid >> 2, sub = tid & 3;
        int nv = nvis[s0 + t];
        const float* lrow = lg + t * 132 + sub * 32;
        int cnt = nv - sub * 32;
        if (cnt < 0) cnt = 0; if (cnt > 32) cnt = 32;
        float mx = -3.0e38f;
        for (int i = 0; i < cnt; i++) mx = fmaxf(mx, lrow[i]);
        mx = fmaxf(mx, __shfl_xor(mx, 1));
        mx = fmaxf(mx, __shfl_xor(mx, 2));
        float sum = 0.f;
        for (int i = 0; i < cnt; i++) sum += __expf(lrow[i] - mx);
        sum += __shfl_xor(sum, 1);
        sum += __shfl_xor(sum, 2);
        float inv = (nv > 0) ? 1.0f / sum : 0.f;
        #pragma unroll 8
        for (int i = 0; i < 32; i++) {
            int m = sub * 32 + i;
            float e = (i < cnt) ? __expf(lrow[i] - mx) * inv : 0.f;
            *(short*)(pPc + ((t * 256 + m * 2) ^ ((t & 7) << 4))) = f2b(e);
        }
    }
    __syncthreads();

    // ---- PV: wave w -> d-cols [w*32, w*32+32) ----
    {
        f32x4 acc[4][2];
        #pragma unroll
        for (int rg = 0; rg < 4; rg++)
            #pragma unroll
            for (int df = 0; df < 2; df++) acc[rg][df] = {0.f, 0.f, 0.f, 0.f};
        #pragma unroll
        for (int kk = 0; kk < 4; kk++) {
            short8v fa[4];
            #pragma unroll
            for (int rg = 0; rg < 4; rg++)
                fa[rg] = *(short8v*)(pPc + (((rg * 16 + lr) * 256 + kk * 64 + lq * 16) ^ ((lr & 7) << 4)));
            #pragma unroll
            for (int df = 0; df < 2; df++) {
                const short8v fb = *(const short8v*)(vT_bf + ((size_t)b << 14)
                                                     + (w * 32 + df * 16 + lr) * 128 + kk * 32 + lq * 8);
                #pragma unroll
                for (int rg = 0; rg < 4; rg++) acc[rg][df] = MFMA(fa[rg], fb, acc[rg][df]);
            }
        }
        #pragma unroll
        for (int rg = 0; rg < 4; rg++)
            #pragma unroll
            for (int df = 0; df < 2; df++)
                #pragma unroll
                for (int r = 0; r < 4; r++) {
                    int row = rg * 16 + lq * 4 + r;
                    int col = w * 32 + df * 16 + lr;
                    *(short*)(odc + ((row * 256 + col * 2) ^ ((row & 7) << 4))) = f2b(acc[rg][df][r]);
                }
    }
    __syncthreads();

    // ---- out-proj: wave w -> rows [w*16, w*16+16), 4 passes of 256 cols ----
    {
        short8v af[4];
        #pragma unroll
        for (int kk = 0; kk < 4; kk++)
            af[kk] = *(short8v*)(odc + (((w * 16 + lr) * 256 + kk * 64 + lq * 16) ^ ((lr & 7) << 4)));
        #pragma unroll
        for (int pass = 0; pass < 4; pass++) {
            int ep = pass * 256;
            f32x4 ac[16];
            #pragma unroll
            for (int e2 = 0; e2 < 16; e2++) ac[e2] = {0.f, 0.f, 0.f, 0.f};
            #pragma unroll
            for (int kk = 0; kk < 4; kk++) {
                #pragma unroll
                for (int e2 = 0; e2 < 16; e2++) {
                    const short8v bb = *(const short8v*)(WoT + (size_t)(ep + e2 * 16 + lr) * 128
                                                         + kk * 32 + lq * 8);
                    ac[e2] = MFMA(af[kk], bb, ac[e2]);
                }
            }
            #pragma unroll
            for (int e2 = 0; e2 < 16; e2++) {
                int col = ep + e2 * 16 + lr;
                float bov = bo[col];
                #pragma unroll
                for (int r = 0; r < 4; r++)
                    out[(s0 + w * 16 + lq * 4 + r) * EMB + col] = ac[e2][r] + bov;
            }
        }
    }
}

extern "C" void kernel_launch(void* const* d_in, const int* in_sizes, int n_in,
                              void* d_out, int out_size, void* d_ws, size_t ws_size,
                              hipStream_t stream) {
    const int*   ids    = (const int*)d_in[0];
    const float* hidden = (const float*)d_in[1];
    const float* Wv     = (const float*)d_in[2];
    const float* bv     = (const float*)d_in[3];
    const float* Wq     = (const float*)d_in[4];
    const float* bq     = (const float*)d_in[5];
    const float* Wk     = (const float*)d_in[6];
    const float* bk     = (const float*)d_in[7];
    const float* Wvt    = (const float*)d_in[8];
    const float* bvt    = (const float*)d_in[9];
    const float* Wo     = (const float*)d_in[10];
    const float* bo     = (const float*)d_in[11];

    char* ws = (char*)d_ws;
    int*   pos   = (int*)ws;                                   // 4 KB
    int*   nvis  = (int*)(ws + (4 << 10));                     // 256 KB
    short* k_bf  = (short*)(ws + (260 << 10));                 // 256 KB
    short* vT_bf = (short*)(ws + (516 << 10));                 // 256 KB
    short* WqT   = (short*)(ws + (772 << 10));                 // 256 KB
    short* WoT   = (short*)(ws + (1028 << 10));                // 256 KB
    short* q_bf  = (short*)(ws + (1284 << 10));                // 16 MB (total ~17.3 MB)

    seg_kernel<<<NB, 1024, 0, stream>>>(ids, pos, nvis);
    prep_w<<<512, 256, 0, stream>>>(Wq, Wo, WqT, WoT);
    dim3 g2(MAX_SEN, NB);
    statkv_kernel<<<g2, 128, 0, stream>>>(hidden, Wv, bv, Wk, bk, Wvt, bvt, pos, k_bf, vT_bf);
    q_kernel<<<NB * SEQ / 64, 256, 0, stream>>>(hidden, WqT, bq, q_bf);
    atto_kernel<<<NB * SEQ / 64, 256, 0, stream>>>(q_bf, k_bf, vT_bf, WoT, bo, nvis,
                                                   (float*)d_out);
}